// Round 14
// baseline (96.322 us; speedup 1.0000x reference)
//
#include <hip/hip_runtime.h>

#define BINS 256
#define HWPIX (512 * 512)     // pixels per channel
#define NCH 192               // B*C = 64*3
#define BPC 32                // blocks per channel
#define NBLK (NCH * BPC)      // 6144 blocks
// per block: 256 threads x 8 float4 = 8192 px; 32 blocks = 262144 = HWPIX

// Workspace:
//   [ done:  NCH u32 tickets ][ pad to 4 KiB ]
//   [ ghist: NCH*BINS int    ]  (both zeroed by the captured memset)
//   [ staged u8 (uint4-packed): NCH*HWPIX bytes ]
//   [ glut: NCH*BINS float ]
#define FLAGS_BYTES  ((size_t)4096)
#define GHIST_BYTES  ((size_t)NCH * BINS * sizeof(int))
#define STAGED_BYTES ((size_t)NCH * HWPIX)

typedef float f4v __attribute__((ext_vector_type(4)));

// Round-14 change vs round 13 (83.0 us): dispatch B and the 6 MB pws
// round-trip are gone. A publishes the histogram via global atomicAdd
// (fabric RMW, rounds 0-3 proven), then the LAST-arriving block of each
// channel (ticket on done[ch] — poll-free, round-8 lesson) reads the
// complete hist via atomicAdd(+0) and computes the LUT in-block.
// C reads glut after the kernel boundary (full visibility, no fences).

// ---------------- Dispatch A: hist + stage + (last block) LUT ----------------
__global__ __launch_bounds__(256) void hist_stage_lut(const float* __restrict__ x,
                                                      unsigned int* __restrict__ done,
                                                      int* __restrict__ ghist,
                                                      uint4* __restrict__ staged4,
                                                      float* __restrict__ glut) {
    __shared__ int h[BINS];
    __shared__ int cum[BINS];
    __shared__ int red[BINS];
    __shared__ unsigned int tick_s;

    const int t = threadIdx.x;
    h[t] = 0;
    __syncthreads();

    const int ch  = blockIdx.x >> 5;
    const int blk = blockIdx.x & 31;
    const f4v* in4 = (const f4v*)(x + (size_t)ch * HWPIX);
    uint4* st4 = staged4 + (size_t)ch * (BPC * 512) + (size_t)blk * 512;
    const int idx0 = blk * 2048 + t;

#pragma unroll
    for (int j = 0; j < 2; ++j) {
        unsigned int p[4];
#pragma unroll
        for (int m = 0; m < 4; ++m) {
            const int k = idx0 + (4 * j + m) * 256;
            f4v v = in4[k];                            // temporal: retain in L3
            int b0 = (int)fminf(fmaxf(floorf(v.x * 255.0f), 0.0f), 255.0f);
            int b1 = (int)fminf(fmaxf(floorf(v.y * 255.0f), 0.0f), 255.0f);
            int b2 = (int)fminf(fmaxf(floorf(v.z * 255.0f), 0.0f), 255.0f);
            int b3 = (int)fminf(fmaxf(floorf(v.w * 255.0f), 0.0f), 255.0f);
            p[m] = (unsigned int)b0 | ((unsigned int)b1 << 8) |
                   ((unsigned int)b2 << 16) | ((unsigned int)b3 << 24);
            atomicAdd(&h[b0], 1);
            atomicAdd(&h[b1], 1);
            atomicAdd(&h[b2], 1);
            atomicAdd(&h[b3], 1);
        }
        uint4 w;
        w.x = p[0]; w.y = p[1]; w.z = p[2]; w.w = p[3];
        st4[j * 256 + t] = w;                          // one 16B store per 16 px
    }
    __syncthreads();

    // publish histogram (fabric RMW); __syncthreads drains vmcnt before the
    // ticket RMW (ordering validated absmax-0 in rounds 5-8)
    atomicAdd(&ghist[ch * BINS + t], h[t]);
    __syncthreads();
    if (t == 0) tick_s = atomicAdd(&done[ch], 1u);
    __syncthreads();

    // ---- last-arriving block computes the channel LUT (no polling) ----
    if (tick_s == BPC - 1) {
        const int hv = atomicAdd(&ghist[ch * BINS + t], 0);   // authoritative
        h[t]   = hv;
        cum[t] = hv;
        red[t] = (hv > 0) ? t : -1;
        __syncthreads();

        for (int off = 128; off > 0; off >>= 1) {      // last nonzero bin index
            if (t < off) red[t] = max(red[t], red[t + off]);
            __syncthreads();
        }
        for (int off = 1; off < BINS; off <<= 1) {     // inclusive scan
            int v = cum[t];
            int a = (t >= off) ? cum[t - off] : 0;
            __syncthreads();
            cum[t] = v + a;
            __syncthreads();
        }

        const int last = h[red[0]];
        const int step = (HWPIX - last) / 255;
        int lutv;
        if (step == 0) {
            lutv = t;                                  // identity channel
        } else if (t == 0) {
            lutv = 0;                                  // shifted-right-by-one head
        } else {
            int val = (cum[t - 1] + (step >> 1)) / step;
            lutv = min(max(val, 0), 255);
        }
        glut[ch * BINS + t] = (float)lutv / 255.0f;    // pre-divide (bit-exact)
    }
}

// ---------------- Dispatch C: apply (wide staged loads + gather + NT stream) ----------
__global__ __launch_bounds__(256) void apply_staged(const uint4* __restrict__ staged4,
                                                    const float* __restrict__ glut,
                                                    float* __restrict__ out) {
    __shared__ float lutf[BINS];
    const int t = threadIdx.x;
    const int ch  = blockIdx.x >> 5;
    const int blk = blockIdx.x & 31;

    lutf[t] = glut[ch * BINS + t];                     // L2-hit, 1 KB
    __syncthreads();

    const uint4* st4 = staged4 + (size_t)ch * (BPC * 512) + (size_t)blk * 512;
    f4v* out4 = (f4v*)(out + (size_t)ch * HWPIX);
    const int idx0 = blk * 2048 + t;

#pragma unroll
    for (int j = 0; j < 2; ++j) {
        const uint4 w = st4[j * 256 + t];              // one 16B load per 16 px
        unsigned int p[4];
        p[0] = w.x; p[1] = w.y; p[2] = w.z; p[3] = w.w;
#pragma unroll
        for (int m = 0; m < 4; ++m) {
            const int k = idx0 + (4 * j + m) * 256;
            const unsigned int pm = p[m];
            f4v o;
            o.x = lutf[pm & 255u];
            o.y = lutf[(pm >> 8) & 255u];
            o.z = lutf[(pm >> 16) & 255u];
            o.w = lutf[pm >> 24];
            __builtin_nontemporal_store(o, &out4[k]);  // never re-read
        }
    }
}

extern "C" void kernel_launch(void* const* d_in, const int* in_sizes, int n_in,
                              void* d_out, int out_size, void* d_ws, size_t ws_size,
                              hipStream_t stream) {
    const float* x = (const float*)d_in[0];
    float* out = (float*)d_out;

    unsigned int* done = (unsigned int*)d_ws;
    int* ghist = (int*)((char*)d_ws + FLAGS_BYTES);
    uint4* staged4 = (uint4*)((char*)d_ws + FLAGS_BYTES + GHIST_BYTES);
    float* glut = (float*)((char*)d_ws + FLAGS_BYTES + GHIST_BYTES + STAGED_BYTES);

    // zero tickets + histograms (captured into the graph, ~200 KB)
    hipMemsetAsync(d_ws, 0, FLAGS_BYTES + GHIST_BYTES, stream);

    hist_stage_lut<<<NBLK, 256, 0, stream>>>(x, done, ghist, staged4, glut);
    apply_staged  <<<NBLK, 256, 0, stream>>>(staged4, glut, out);
}

// Round 15
// 83.049 us; speedup vs baseline: 1.1598x; 1.1598x over previous
//
#include <hip/hip_runtime.h>

#define BINS 256
#define HWPIX (512 * 512)     // pixels per channel
#define NCH 192               // B*C = 64*3
#define BPC 32                // blocks per channel
#define NBLK (NCH * BPC)      // 6144 blocks
// per block: 256 threads x 8 float4 = 8192 px; 32 blocks = 262144 = HWPIX

// Workspace: [ pws: NBLK*BINS int = 6 MB ][ staged u8: NCH*HWPIX = 50 MB ][ glut: 192 KB ]
#define PWS_BYTES    ((size_t)NBLK * BINS * sizeof(int))
#define STAGED_BYTES ((size_t)NCH * HWPIX)

typedef float f4v __attribute__((ext_vector_type(4)));

// CHAMPION (round 12, 82.95 us) — re-submitted after round 14's fusion
// regression. Session lessons baked into this structure:
//  - temporal input loads (L3-resident across dispatches/replays): -5.5 us
//  - staged u8 (50 MB) instead of re-reading fp32 (201 MB): -1.5 us vs re-read
//  - hoisted per-channel LUT to its own 192-block dispatch: -3 us
//  - wide 16B staged path: -1 us
//  - NT stores on output only (never re-read; don't pollute L3)
//  - non-atomic pws + kernel-boundary visibility: every sync-fusion
//    alternative (coop-launch, acquire-spin, RMW-poll, ticket+global-atomics)
//    regressed by +13..+1040 us (rounds 2,6,7,8,14)
//  - neutral (hidden under stream): banked conflict-free LDS hist (r13),
//    VMEM issue width (r12 delta was ~1 us)

// ---------------- Dispatch A: histogram (non-atomic partials) + stage u8 (wide) --------
__global__ __launch_bounds__(256) void hist_stage(const float* __restrict__ x,
                                                  int* __restrict__ pws,
                                                  uint4* __restrict__ staged4) {
    __shared__ int h[BINS];
    const int t = threadIdx.x;
    h[t] = 0;
    __syncthreads();

    const int ch  = blockIdx.x >> 5;
    const int blk = blockIdx.x & 31;
    const f4v* in4 = (const f4v*)(x + (size_t)ch * HWPIX);
    uint4* st4 = staged4 + (size_t)ch * (BPC * 512) + (size_t)blk * 512;
    const int idx0 = blk * 2048 + t;

#pragma unroll
    for (int j = 0; j < 2; ++j) {
        unsigned int p[4];
#pragma unroll
        for (int m = 0; m < 4; ++m) {
            const int k = idx0 + (4 * j + m) * 256;
            f4v v = in4[k];                            // temporal: retain in L3
            int b0 = (int)fminf(fmaxf(floorf(v.x * 255.0f), 0.0f), 255.0f);
            int b1 = (int)fminf(fmaxf(floorf(v.y * 255.0f), 0.0f), 255.0f);
            int b2 = (int)fminf(fmaxf(floorf(v.z * 255.0f), 0.0f), 255.0f);
            int b3 = (int)fminf(fmaxf(floorf(v.w * 255.0f), 0.0f), 255.0f);
            p[m] = (unsigned int)b0 | ((unsigned int)b1 << 8) |
                   ((unsigned int)b2 << 16) | ((unsigned int)b3 << 24);
            atomicAdd(&h[b0], 1);
            atomicAdd(&h[b1], 1);
            atomicAdd(&h[b2], 1);
            atomicAdd(&h[b3], 1);
        }
        uint4 w;
        w.x = p[0]; w.y = p[1]; w.z = p[2]; w.w = p[3];
        st4[j * 256 + t] = w;                          // one 16B store per 16 px
    }
    __syncthreads();
    pws[(size_t)blockIdx.x * BINS + t] = h[t];         // non-atomic, coalesced
}

// ---------------- Dispatch B: per-channel LUT, computed ONCE (192 blocks) ----------------
__global__ __launch_bounds__(256) void lut_kernel(const int* __restrict__ pws,
                                                  float* __restrict__ glut) {
    __shared__ int h[BINS];
    __shared__ int cum[BINS];
    __shared__ int red[BINS];
    const int t = threadIdx.x;
    const int ch = blockIdx.x;

    const int* base = pws + (size_t)ch * BPC * BINS;
    int s = 0;
#pragma unroll
    for (int b = 0; b < BPC; ++b) s += base[b * BINS + t];
    h[t]   = s;
    cum[t] = s;
    red[t] = (s > 0) ? t : -1;
    __syncthreads();

    for (int off = 128; off > 0; off >>= 1) {          // last nonzero bin index
        if (t < off) red[t] = max(red[t], red[t + off]);
        __syncthreads();
    }
    for (int off = 1; off < BINS; off <<= 1) {         // inclusive scan
        int v = cum[t];
        int a = (t >= off) ? cum[t - off] : 0;
        __syncthreads();
        cum[t] = v + a;
        __syncthreads();
    }

    const int last = h[red[0]];
    const int step = (HWPIX - last) / 255;
    int lutv;
    if (step == 0) {
        lutv = t;                                      // identity channel
    } else if (t == 0) {
        lutv = 0;                                      // shifted-right-by-one head
    } else {
        int val = (cum[t - 1] + (step >> 1)) / step;
        lutv = min(max(val, 0), 255);
    }
    glut[ch * BINS + t] = (float)lutv / 255.0f;        // pre-divide (bit-exact w/ ref)
}

// ---------------- Dispatch C: apply (wide staged loads + gather + NT stream) ----------
__global__ __launch_bounds__(256) void apply_staged(const uint4* __restrict__ staged4,
                                                    const float* __restrict__ glut,
                                                    float* __restrict__ out) {
    __shared__ float lutf[BINS];
    const int t = threadIdx.x;
    const int ch  = blockIdx.x >> 5;
    const int blk = blockIdx.x & 31;

    lutf[t] = glut[ch * BINS + t];                     // L2-hit, 1 KB
    __syncthreads();

    const uint4* st4 = staged4 + (size_t)ch * (BPC * 512) + (size_t)blk * 512;
    f4v* out4 = (f4v*)(out + (size_t)ch * HWPIX);
    const int idx0 = blk * 2048 + t;

#pragma unroll
    for (int j = 0; j < 2; ++j) {
        const uint4 w = st4[j * 256 + t];              // one 16B load per 16 px
        unsigned int p[4];
        p[0] = w.x; p[1] = w.y; p[2] = w.z; p[3] = w.w;
#pragma unroll
        for (int m = 0; m < 4; ++m) {
            const int k = idx0 + (4 * j + m) * 256;
            const unsigned int pm = p[m];
            f4v o;
            o.x = lutf[pm & 255u];
            o.y = lutf[(pm >> 8) & 255u];
            o.z = lutf[(pm >> 16) & 255u];
            o.w = lutf[pm >> 24];
            __builtin_nontemporal_store(o, &out4[k]);  // never re-read
        }
    }
}

extern "C" void kernel_launch(void* const* d_in, const int* in_sizes, int n_in,
                              void* d_out, int out_size, void* d_ws, size_t ws_size,
                              hipStream_t stream) {
    const float* x = (const float*)d_in[0];
    float* out = (float*)d_out;

    int* pws = (int*)d_ws;
    uint4* staged4 = (uint4*)((char*)d_ws + PWS_BYTES);
    float* glut = (float*)((char*)d_ws + PWS_BYTES + STAGED_BYTES);

    hist_stage  <<<NBLK, 256, 0, stream>>>(x, pws, staged4);
    lut_kernel  <<<NCH,  256, 0, stream>>>(pws, glut);
    apply_staged<<<NBLK, 256, 0, stream>>>(staged4, glut, out);
}